// Round 1
// baseline (425.179 us; speedup 1.0000x reference)
//
#include <hip/hip_runtime.h>
#include <hip/hip_cooperative_groups.h>
#include <math.h>

namespace cg = cooperative_groups;

// Problem constants
#define NBH 32     // B*KVH = 4*8
#define HPKN 4
#define DN 128
#define SEQKV 4096
#define SEQN 4097
#define SSTR 4100  // padded score-row stride (keeps float4 alignment per row)
#define RANKN 32
#define KSEL 516   // K + SINK = 512 + 4
#define SINKN 4
#define LOCALK 128 // masked-local region starts at SEQKV - LOCALK = 3968
#define NMASK 132  // SINKN + LOCALK
#define NTOP 384   // KSEL - NMASK
#define NCHUNK 16  // k2 position-chunks per bh

// ---------------------------------------------------------------------------
// Single cooperative kernel, 5 phases separated by grid.sync():
//   P1 = old k2 (approx scores + partials), 512 blocks (16 chunks x 32 bh)
//   P2 = old k3 (top-384 radix select + sort), 32 active blocks
//   P3 = old k5 (gathered QK^T), 512 blocks, 33 j's per block
//   P4 = old k6 (kv_weight + softmax + out init), 128 active blocks
//   P5 = old k7 (out += W*V_g), 512 blocks, 33 j's per block
// Shared memory: one 45.3 KB arena re-aliased per phase (P2 dominates).
// grid 512, block 256. LDS 45.3KB -> 3 blocks/CU; coop needs 2/CU. OK.
// ---------------------------------------------------------------------------
__global__ __launch_bounds__(256, 2) void fused_all(
    const float* __restrict__ q, const float* __restrict__ key,
    const float* __restrict__ value, const float* __restrict__ lm,
    const float* __restrict__ key_cpu, const float* __restrict__ value_cpu,
    const float* __restrict__ skey, const float* __restrict__ mean_v,
    float* __restrict__ scores, float* __restrict__ tk,
    float2* __restrict__ partials, int* __restrict__ indices,
    float* __restrict__ s2_g, float* __restrict__ w_g,
    float* __restrict__ out, float* __restrict__ out_w) {
  cg::grid_group grid = cg::this_grid();
  const int bid = blockIdx.x;
  const int bh = bid >> 4;      // [0,32)
  const int chunk = bid & 15;   // [0,16)
  const int t = threadIdx.x;
  const int wave = t >> 6, lane = t & 63;

  __shared__ __align__(16) char smem[45248];
  __shared__ int c1, c2, binB_s, nAbove_s, needed_s;
  __shared__ float bc6;

  // ======================= Phase 1: approximate scores =====================
  {
    float* qv = (float*)smem;        // [4][128]
    float* absq = qv + 512;          // [128]
    int* sel = (int*)(absq + 128);   // [32]
    float* qp = (float*)(sel + 32);  // [4][32]
    float* wred = qp + 128;          // [4][4]
    const int s0 = chunk << 8;

    {
      float v0 = q[(size_t)bh * 512 + t];
      float v1 = q[(size_t)bh * 512 + 256 + t];
      qv[(t >> 7) * 128 + (t & 127)] = v0;
      qv[(2 + (t >> 7)) * 128 + (t & 127)] = v1;
    }
    __syncthreads();
    if (t < 128)
      absq[t] = fabsf(qv[t]) + fabsf(qv[128 + t]) + fabsf(qv[256 + t]) +
                fabsf(qv[384 + t]);
    __syncthreads();
    if (t < 128) {
      float a = absq[t];
      int rank = 0;
      for (int e = 0; e < 128; ++e) {
        float ae = absq[e];
        rank += (ae > a) || (ae == a && e < t);
      }
      if (rank < RANKN) sel[rank] = t;
    }
    __syncthreads();
    // per-p (wave==p) full |q| sum and selected |q| sum via shuffles
    {
      float fa = fabsf(qv[wave * 128 + lane]) + fabsf(qv[wave * 128 + lane + 64]);
      for (int off = 32; off > 0; off >>= 1) fa += __shfl_down(fa, off);
      float full = __shfl(fa, 0);
      float qsel = (lane < RANKN) ? qv[wave * 128 + sel[lane]] : 0.f;
      float sv = fabsf(qsel);
      for (int off = 32; off > 0; off >>= 1) sv += __shfl_down(sv, off);
      float selsum = __shfl(sv, 0);
      float scale = sqrtf(selsum / full * 128.f);
      if (lane < RANKN) qp[wave * RANKN + lane] = qsel / scale;
    }
    __syncthreads();

    // current-token score (chunk==0 only; wave == p)
    if (chunk == 0) {
      float kv = (lane < RANKN) ? key[bh * 128 + sel[lane]] : 0.f;
      float pr = (lane < RANKN) ? qp[wave * RANKN + lane] * kv : 0.f;
      for (int off = 32; off > 0; off >>= 1) pr += __shfl_down(pr, off);
      if (lane == 0)
        scores[(size_t)(bh * 4 + wave) * SSTR + SEQKV] =
            pr + lm[(size_t)(bh * 4 + wave) * SEQN + SEQKV];
    }

    // main approximate-score loop over this 256-position chunk
    const float* kb = skey + (size_t)bh * 128 * 4096;
    float a0 = 0, a1 = 0, a2 = 0, a3 = 0;
#pragma unroll 8
    for (int r = 0; r < RANKN; ++r) {
      float k0 = kb[((size_t)sel[r] << 12) + s0 + t];
      a0 += qp[0 * RANKN + r] * k0;
      a1 += qp[1 * RANKN + r] * k0;
      a2 += qp[2 * RANKN + r] * k0;
      a3 += qp[3 * RANKN + r] * k0;
    }
    float sc[4];
    {
      int s = s0 + t;
      sc[0] = a0 + lm[(size_t)(bh * 4 + 0) * SEQN + s];
      sc[1] = a1 + lm[(size_t)(bh * 4 + 1) * SEQN + s];
      sc[2] = a2 + lm[(size_t)(bh * 4 + 2) * SEQN + s];
      sc[3] = a3 + lm[(size_t)(bh * 4 + 3) * SEQN + s];
      float sum = sc[0] + sc[1] + sc[2] + sc[3];
#pragma unroll
      for (int p = 0; p < 4; ++p)
        scores[(size_t)(bh * 4 + p) * SSTR + s] = sc[p];
      tk[(bh << 12) + s] = sum;
    }

    // per-chunk softmax partials (max, sum-exp) per p
#pragma unroll
    for (int p = 0; p < 4; ++p) {
      float mx = sc[p];
      for (int off = 32; off > 0; off >>= 1) mx = fmaxf(mx, __shfl_down(mx, off));
      if (lane == 0) wred[wave * 4 + p] = mx;
    }
    __syncthreads();
    float bm[4];
#pragma unroll
    for (int p = 0; p < 4; ++p)
      bm[p] = fmaxf(fmaxf(wred[0 * 4 + p], wred[1 * 4 + p]),
                    fmaxf(wred[2 * 4 + p], wred[3 * 4 + p]));
    __syncthreads();  // wred reuse
#pragma unroll
    for (int p = 0; p < 4; ++p) {
      float e = expf(sc[p] - bm[p]);
      for (int off = 32; off > 0; off >>= 1) e += __shfl_down(e, off);
      if (lane == 0) wred[wave * 4 + p] = e;
    }
    __syncthreads();
    if (t < 4) {
      float s = wred[0 * 4 + t] + wred[1 * 4 + t] + wred[2 * 4 + t] + wred[3 * 4 + t];
      partials[(size_t)(bh * 4 + t) * NCHUNK + chunk] = make_float2(bm[t], s);
    }
  }

  grid.sync();

  // ======================= Phase 2: top-k select ===========================
  if (chunk == 0) {
    unsigned* us = (unsigned*)smem;                                     // 4096
    unsigned* hist = us + 4096;                                         // 2048
    unsigned long long* binlist = (unsigned long long*)(hist + 2048);   // 2048
    unsigned long long* selk = binlist + 2048;                          // 512
    unsigned* chunkSum = (unsigned*)(selk + 512);                       // 32

    {
      const float4* tk4 = (const float4*)(tk + (bh << 12));
      for (int i = t; i < 1024; i += 256) {
        float4 v = tk4[i];
        unsigned b0 = __float_as_uint(v.x), b1 = __float_as_uint(v.y);
        unsigned b2 = __float_as_uint(v.z), b3 = __float_as_uint(v.w);
        us[i * 4 + 0] = (b0 & 0x80000000u) ? ~b0 : (b0 | 0x80000000u);
        us[i * 4 + 1] = (b1 & 0x80000000u) ? ~b1 : (b1 | 0x80000000u);
        us[i * 4 + 2] = (b2 & 0x80000000u) ? ~b2 : (b2 | 0x80000000u);
        us[i * 4 + 3] = (b3 & 0x80000000u) ? ~b3 : (b3 | 0x80000000u);
      }
    }
    for (int i = t; i < 2048; i += 256) hist[i] = 0;
    if (t == 0) { c1 = 0; c2 = 0; }
    __syncthreads();

    // histogram of candidates s in [SINKN, SEQKV-LOCALK) on top 11 bits
    for (int s = SINKN + t; s < SEQKV - LOCALK; s += 256)
      atomicAdd(&hist[us[s] >> 21], 1u);
    __syncthreads();

    if (t < 32) {
      unsigned sum = 0;
      for (int i = 0; i < 64; ++i) sum += hist[t * 64 + i];
      chunkSum[t] = sum;
    }
    __syncthreads();

    if (t < 64) {
      int l = t;
      unsigned x = (l < 32) ? chunkSum[l] : 0;
      unsigned sfx = x;
      for (int off = 1; off < 64; off <<= 1) {
        unsigned y = __shfl_down(sfx, off);
        if (l + off < 64) sfx += y;
      }
      unsigned above = sfx - x;
      bool hit = (l < 32) && (above < NTOP) && (above + x >= NTOP);
      unsigned long long mask = __ballot(hit);
      int C = __ffsll(mask) - 1;
      unsigned aboveC = __shfl(above, C);
      unsigned h = hist[C * 64 + l];
      unsigned sfx2 = h;
      for (int off = 1; off < 64; off <<= 1) {
        unsigned y = __shfl_down(sfx2, off);
        if (l + off < 64) sfx2 += y;
      }
      unsigned above2 = aboveC + (sfx2 - h);
      bool hit2 = (above2 < NTOP) && (above2 + h >= NTOP);
      unsigned long long mask2 = __ballot(hit2);
      int lB = __ffsll(mask2) - 1;
      if (l == lB) {
        binB_s = C * 64 + l;
        nAbove_s = (int)above2;
        needed_s = NTOP - (int)above2;
      }
    }
    __syncthreads();
    unsigned binB = (unsigned)binB_s;
    int nAbove = nAbove_s, needed = needed_s;

    // collect: definite winners -> selk, boundary-bin members -> binlist
    for (int s0 = SINKN; s0 < SEQKV - LOCALK; s0 += 256) {
      int s = s0 + t;
      bool valid = (s < SEQKV - LOCALK);
      unsigned u = valid ? us[s] : 0u;
      unsigned bin = u >> 21;
      bool win = valid && (bin > binB);
      bool bnd = valid && (bin == binB);
      unsigned long long mw = __ballot(win);
      unsigned long long mb = __ballot(bnd);
      int bw = 0, bb = 0;
      if (lane == 0) {
        if (mw) bw = atomicAdd(&c1, __popcll(mw));
        if (mb) bb = atomicAdd(&c2, __popcll(mb));
      }
      bw = __shfl(bw, 0);
      bb = __shfl(bb, 0);
      unsigned long long lmask = (1ULL << lane) - 1ULL;
      unsigned long long keyv = ((unsigned long long)u << 32) | (unsigned)(~s);
      if (win) selk[bw + __popcll(mw & lmask)] = keyv;
      if (bnd) {
        int pos = bb + __popcll(mb & lmask);
        if (pos < 2048) binlist[pos] = keyv;
      }
    }
    __syncthreads();
    int m2 = c2;
    int p2 = 1;
    while (p2 < m2) p2 <<= 1;
    for (int i = m2 + t; i < p2; i += 256) binlist[i] = 0ULL;
    __syncthreads();
    // bitonic sort (descending) of the boundary bin
    for (int k = 2; k <= p2; k <<= 1)
      for (int j = k >> 1; j > 0; j >>= 1) {
        for (int i = t; i < p2; i += 256) {
          int ixj = i ^ j;
          if (ixj > i) {
            bool desc = ((i & k) == 0);
            unsigned long long a = binlist[i], bb2 = binlist[ixj];
            if ((a < bb2) == desc) { binlist[i] = bb2; binlist[ixj] = a; }
          }
        }
        __syncthreads();
      }
    for (int i = t; i < needed; i += 256) selk[nAbove + i] = binlist[i];
    for (int i = NTOP + t; i < 512; i += 256) selk[i] = 0ULL;
    __syncthreads();

    // hybrid register bitonic sort (descending) of 512
    unsigned long long e0 = selk[t], e1 = selk[t + 256];
    int i1 = t + 256;
    for (int k = 2; k <= 512; k <<= 1) {
      for (int j = k >> 1; j > 0; j >>= 1) {
        if (j == 256) {
          if (e0 < e1) { unsigned long long tmp = e0; e0 = e1; e1 = tmp; }
        } else if (j >= 64) {
          selk[t] = e0; selk[i1] = e1;
          __syncthreads();
          unsigned long long p0 = selk[t ^ j], p1 = selk[i1 ^ j];
          __syncthreads();
          bool d0 = ((t & k) == 0), l0 = ((t & j) == 0);
          e0 = (d0 == l0) ? (e0 > p0 ? e0 : p0) : (e0 < p0 ? e0 : p0);
          bool d1 = ((i1 & k) == 0), l1 = ((i1 & j) == 0);
          e1 = (d1 == l1) ? (e1 > p1 ? e1 : p1) : (e1 < p1 ? e1 : p1);
        } else {
          unsigned long long p0 = __shfl_xor(e0, j);
          unsigned long long p1 = __shfl_xor(e1, j);
          bool d0 = ((t & k) == 0), l0 = ((t & j) == 0);
          e0 = (d0 == l0) ? (e0 > p0 ? e0 : p0) : (e0 < p0 ? e0 : p0);
          bool d1 = ((i1 & k) == 0);
          e1 = (d1 == l0) ? (e1 > p1 ? e1 : p1) : (e1 < p1 ? e1 : p1);
        }
      }
    }

    // emit: masked first (index-ascending), then top-384 descending
    if (t < SINKN) indices[bh * KSEL + t] = t;
    for (int i = t; i < LOCALK; i += 256)
      indices[bh * KSEL + SINKN + i] = (SEQKV - LOCALK) + i;
    indices[bh * KSEL + NMASK + t] = (int)(~(unsigned)(e0 & 0xFFFFFFFFu));
    if (t < NTOP - 256)
      indices[bh * KSEL + NMASK + 256 + t] = (int)(~(unsigned)(e1 & 0xFFFFFFFFu));
  }

  grid.sync();

  // ======================= Phase 3: gathered QK^T ==========================
  {
    float* qs = (float*)smem;       // [512]
    int* sidx = (int*)(qs + 512);   // [516]
    qs[t] = q[((size_t)bh << 9) + t];
    qs[t + 256] = q[((size_t)bh << 9) + t + 256];
    for (int j = t; j < KSEL; j += 256) sidx[j] = indices[bh * KSEL + j];
    __syncthreads();

    const float rsqd = 0.08838834764831845f;  // 1/sqrt(128)
    float q0a = qs[lane * 2], q0b = qs[lane * 2 + 1];
    float q1a = qs[128 + lane * 2], q1b = qs[128 + lane * 2 + 1];
    float q2a = qs[256 + lane * 2], q2b = qs[256 + lane * 2 + 1];
    float q3a = qs[384 + lane * 2], q3b = qs[384 + lane * 2 + 1];

    for (int m = wave; m < 33; m += 4) {
      int j = chunk + (m << 4);
      if (j > KSEL) continue;
      int sj = (j < KSEL) ? sidx[j] : SEQKV;
      const float* krow = (j < KSEL)
          ? key_cpu + ((((size_t)bh << 12) + sj) << 7)
          : key + ((size_t)bh << 7);
      float2 kk = ((const float2*)krow)[lane];
      float p0 = q0a * kk.x + q0b * kk.y;
      float p1 = q1a * kk.x + q1b * kk.y;
      float p2 = q2a * kk.x + q2b * kk.y;
      float p3 = q3a * kk.x + q3b * kk.y;
      for (int off = 32; off > 0; off >>= 1) {
        p0 += __shfl_down(p0, off);
        p1 += __shfl_down(p1, off);
        p2 += __shfl_down(p2, off);
        p3 += __shfl_down(p3, off);
      }
      if (lane == 0) {
        size_t lmb = (size_t)bh * 4 * SEQN + sj;
        s2_g[(bh * 4 + 0) * 520 + j] = p0 * rsqd + lm[lmb + 0 * SEQN];
        s2_g[(bh * 4 + 1) * 520 + j] = p1 * rsqd + lm[lmb + 1 * SEQN];
        s2_g[(bh * 4 + 2) * 520 + j] = p2 * rsqd + lm[lmb + 2 * SEQN];
        s2_g[(bh * 4 + 3) * 520 + j] = p3 * rsqd + lm[lmb + 3 * SEQN];
      }
    }
  }

  grid.sync();

  // ======================= Phase 4: stats + softmax ========================
  if (bid < 128) {
    const int bhp = bid;
    const int bh4 = bhp >> 2;
    int* sidx = (int*)smem;             // [516]
    float* red = (float*)(sidx + 520);  // [256]

    for (int j = t; j < KSEL; j += 256) sidx[j] = indices[bh4 * KSEL + j];
    __syncthreads();

    const float* srow = scores + (size_t)bhp * SSTR;
    float cur = srow[SEQKV];

    float m = cur, sumexp;
    {
      float2 pc[NCHUNK];
#pragma unroll
      for (int c = 0; c < NCHUNK; ++c) {
        pc[c] = partials[(size_t)bhp * NCHUNK + c];
        m = fmaxf(m, pc[c].x);
      }
      float s = expf(cur - m);
#pragma unroll
      for (int c = 0; c < NCHUNK; ++c) s += pc[c].y * expf(pc[c].x - m);
      sumexp = s;
    }

    float ss = 0.f;
    for (int j = t; j < KSEL; j += 256) ss += expf(srow[sidx[j]] - m);
    red[t] = ss; __syncthreads();
    for (int st = 128; st > 0; st >>= 1) {
      if (t < st) red[t] += red[t + st];
      __syncthreads();
    }
    if (t == 0) bc6 = (red[0] + expf(cur - m)) / sumexp;
    __syncthreads();
    float kvw = bc6; __syncthreads();

    const float* s2r = s2_g + (size_t)bhp * 520;
    float mx2 = -INFINITY;
    for (int j = t; j < KSEL + 1; j += 256) mx2 = fmaxf(mx2, s2r[j]);
    red[t] = mx2; __syncthreads();
    for (int st = 128; st > 0; st >>= 1) {
      if (t < st) red[t] = fmaxf(red[t], red[t + st]);
      __syncthreads();
    }
    float m2 = red[0]; __syncthreads();
    float se2 = 0.f;
    for (int j = t; j < KSEL + 1; j += 256) se2 += expf(s2r[j] - m2);
    red[t] = se2; __syncthreads();
    for (int st = 128; st > 0; st >>= 1) {
      if (t < st) red[t] += red[t + st];
      __syncthreads();
    }
    float inv = kvw / red[0];

    for (int j = t; j < KSEL + 1; j += 256) {
      float w = expf(s2r[j] - m2) * inv;
      out_w[(size_t)bhp * (KSEL + 1) + j] = w;
      w_g[(size_t)bhp * 520 + j] = w;
    }

    if (t < 128) {
      float vcur = value[((size_t)bh4 << 7) + t];
      float mvn = (mean_v[((size_t)bh4 << 7) + t] * 4096.f + vcur) / 4097.f;
      out[((size_t)bhp << 7) + t] = (1.f - kvw) * mvn;
    }
  }

  grid.sync();

  // ======================= Phase 5: out += W * V_g =========================
  {
    const int c0 = chunk * 33;
    const int nj = min(33, KSEL + 1 - c0);
    const int d = t & 127, half = t >> 7;
    int* sidx = (int*)smem;            // [33] (+pad)
    float* wsh = (float*)(sidx + 36);  // [4][33]
    float* red = wsh + 136;            // [2][4][128]

    if (t < nj) {
      int j = c0 + t;
      sidx[t] = (j < KSEL) ? indices[bh * KSEL + j] : -1;
    }
    if (t < 33) {
#pragma unroll
      for (int p = 0; p < 4; ++p)
        wsh[p * 33 + t] = (t < nj) ? w_g[(size_t)(bh * 4 + p) * 520 + c0 + t] : 0.f;
    }
    __syncthreads();

    float a0 = 0, a1 = 0, a2 = 0, a3 = 0;
    for (int jl = half; jl < nj; jl += 2) {
      int sj = sidx[jl];
      const float* vrow = (sj >= 0)
          ? value_cpu + ((((size_t)bh << 12) + sj) << 7)
          : value + ((size_t)bh << 7);
      float v = vrow[d];
      a0 += wsh[0 * 33 + jl] * v;
      a1 += wsh[1 * 33 + jl] * v;
      a2 += wsh[2 * 33 + jl] * v;
      a3 += wsh[3 * 33 + jl] * v;
    }
    red[(half * 4 + 0) * 128 + d] = a0;
    red[(half * 4 + 1) * 128 + d] = a1;
    red[(half * 4 + 2) * 128 + d] = a2;
    red[(half * 4 + 3) * 128 + d] = a3;
    __syncthreads();
    if (half == 0) {
#pragma unroll
      for (int p = 0; p < 4; ++p) {
        float s = red[(0 * 4 + p) * 128 + d] + red[(1 * 4 + p) * 128 + d];
        atomicAdd(&out[(size_t)(bh * 4 + p) * 128 + d], s);
      }
    }
  }
}

// ---------------------------------------------------------------------------
extern "C" void kernel_launch(void* const* d_in, const int* in_sizes, int n_in,
                              void* d_out, int out_size, void* d_ws, size_t ws_size,
                              hipStream_t stream) {
  const float* query     = (const float*)d_in[0];
  const float* key       = (const float*)d_in[1];
  const float* value     = (const float*)d_in[2];
  const float* logmask   = (const float*)d_in[3];
  const float* key_cpu   = (const float*)d_in[4];
  const float* value_cpu = (const float*)d_in[5];
  const float* s_key_cpu = (const float*)d_in[6];
  const float* mean_v    = (const float*)d_in[7];

  float* out   = (float*)d_out;       // (4,32,1,128) = 16384 floats
  float* out_w = out + 16384;         // (4,32,1,517) = 66176 floats

  char* ws = (char*)d_ws;
  int*    indices  = (int*)(ws + 20480);          // 66048 B
  float*  scores   = (float*)(ws + 86528);        // 128*4100*4 = 2099200 B
  float*  tk       = (float*)(ws + 2185728);      // 524288 B
  float*  s2_g     = (float*)(ws + 2710016);      // 266240 B
  float*  w_g      = (float*)(ws + 2976256);      // 266240 B
  float2* partials = (float2*)(ws + 3242496);     // 128*16*8 = 16384 B

  void* args[] = {
      (void*)&query, (void*)&key, (void*)&value, (void*)&logmask,
      (void*)&key_cpu, (void*)&value_cpu, (void*)&s_key_cpu, (void*)&mean_v,
      (void*)&scores, (void*)&tk, (void*)&partials, (void*)&indices,
      (void*)&s2_g, (void*)&w_g, (void*)&out, (void*)&out_w};
  hipLaunchCooperativeKernel((void*)fused_all, dim3(512), dim3(256), args, 0,
                             stream);
}

// Round 2
// 258.119 us; speedup vs baseline: 1.6472x; 1.6472x over previous
//
#include <hip/hip_runtime.h>
#include <math.h>

// Problem constants
#define NBH 32     // B*KVH = 4*8
#define HPKN 4
#define DN 128
#define SEQKV 4096
#define SEQN 4097
#define SSTR 4100  // padded score-row stride (keeps float4 alignment per row)
#define RANKN 32
#define KSEL 516   // K + SINK = 512 + 4
#define SINKN 4
#define LOCALK 128 // masked-local region starts at SEQKV - LOCALK = 3968
#define NMASK 132  // SINKN + LOCALK
#define NTOP 384   // KSEL - NMASK
#define NCHUNK 16  // k2 position-chunks per bh

// ---------------------------------------------------------------------------
// Kernel 2: per block, recompute rank-32 dim selection + scales from q via
// shuffle reductions, then approximate scores over this block's 256-position
// chunk. Emits per-chunk softmax partials (max, sum-exp) per (bh,p).
// Block x==0 also writes the current-token (s=4096) score.
// grid (16, 32 bh), block 256.  [UNCHANGED from the 229 us baseline]
// ---------------------------------------------------------------------------
__global__ __launch_bounds__(256) void k2_scores(
    const float* __restrict__ q, const float* __restrict__ key,
    const float* __restrict__ skey, const float* __restrict__ lm,
    float* __restrict__ scores, float* __restrict__ tk,
    float2* __restrict__ partials) {
  int bh = blockIdx.y;
  int s0 = blockIdx.x << 8;
  int t = threadIdx.x;
  int wave = t >> 6, lane = t & 63;
  __shared__ float qv[4][128];
  __shared__ float absq[128];
  __shared__ int sel[RANKN];
  __shared__ float qp[4][RANKN];
  __shared__ float wred[4][4];

  {
    float v0 = q[(size_t)bh * 512 + t];
    float v1 = q[(size_t)bh * 512 + 256 + t];
    qv[t >> 7][t & 127] = v0;
    qv[2 + (t >> 7)][t & 127] = v1;
  }
  __syncthreads();
  if (t < 128)
    absq[t] = fabsf(qv[0][t]) + fabsf(qv[1][t]) + fabsf(qv[2][t]) + fabsf(qv[3][t]);
  __syncthreads();
  if (t < 128) {
    float a = absq[t];
    int rank = 0;
    for (int e = 0; e < 128; ++e) {
      float ae = absq[e];
      rank += (ae > a) || (ae == a && e < t);
    }
    if (rank < RANKN) sel[rank] = t;
  }
  __syncthreads();
  {
    float fa = fabsf(qv[wave][lane]) + fabsf(qv[wave][lane + 64]);
    for (int off = 32; off > 0; off >>= 1) fa += __shfl_down(fa, off);
    float full = __shfl(fa, 0);
    float qsel = (lane < RANKN) ? qv[wave][sel[lane]] : 0.f;
    float sv = fabsf(qsel);
    for (int off = 32; off > 0; off >>= 1) sv += __shfl_down(sv, off);
    float selsum = __shfl(sv, 0);
    float scale = sqrtf(selsum / full * 128.f);
    if (lane < RANKN) qp[wave][lane] = qsel / scale;
  }
  __syncthreads();

  if (blockIdx.x == 0) {
    float kv = (lane < RANKN) ? key[bh * 128 + sel[lane]] : 0.f;
    float pr = (lane < RANKN) ? qp[wave][lane] * kv : 0.f;
    for (int off = 32; off > 0; off >>= 1) pr += __shfl_down(pr, off);
    if (lane == 0)
      scores[(size_t)(bh * 4 + wave) * SSTR + SEQKV] =
          pr + lm[(size_t)(bh * 4 + wave) * SEQN + SEQKV];
  }

  const float* kb = skey + (size_t)bh * 128 * 4096;
  float a0 = 0, a1 = 0, a2 = 0, a3 = 0;
#pragma unroll 8
  for (int r = 0; r < RANKN; ++r) {
    float k0 = kb[((size_t)sel[r] << 12) + s0 + t];
    a0 += qp[0][r] * k0;
    a1 += qp[1][r] * k0;
    a2 += qp[2][r] * k0;
    a3 += qp[3][r] * k0;
  }
  float sc[4];
  {
    int s = s0 + t;
    sc[0] = a0 + lm[(size_t)(bh * 4 + 0) * SEQN + s];
    sc[1] = a1 + lm[(size_t)(bh * 4 + 1) * SEQN + s];
    sc[2] = a2 + lm[(size_t)(bh * 4 + 2) * SEQN + s];
    sc[3] = a3 + lm[(size_t)(bh * 4 + 3) * SEQN + s];
    float sum = sc[0] + sc[1] + sc[2] + sc[3];
#pragma unroll
    for (int p = 0; p < 4; ++p)
      scores[(size_t)(bh * 4 + p) * SSTR + s] = sc[p];
    tk[(bh << 12) + s] = sum;
  }

#pragma unroll
  for (int p = 0; p < 4; ++p) {
    float mx = sc[p];
    for (int off = 32; off > 0; off >>= 1) mx = fmaxf(mx, __shfl_down(mx, off));
    if (lane == 0) wred[wave][p] = mx;
  }
  __syncthreads();
  float bm[4];
#pragma unroll
  for (int p = 0; p < 4; ++p)
    bm[p] = fmaxf(fmaxf(wred[0][p], wred[1][p]), fmaxf(wred[2][p], wred[3][p]));
  __syncthreads();  // wred reuse
#pragma unroll
  for (int p = 0; p < 4; ++p) {
    float e = expf(sc[p] - bm[p]);
    for (int off = 32; off > 0; off >>= 1) e += __shfl_down(e, off);
    if (lane == 0) wred[wave][p] = e;
  }
  __syncthreads();
  if (t < 4) {
    float s = wred[0][t] + wred[1][t] + wred[2][t] + wred[3][t];
    partials[(size_t)(bh * 4 + t) * NCHUNK + blockIdx.x] = make_float2(bm[t], s);
  }
}

// ---------------------------------------------------------------------------
// Kernel 3: top-384-of-3964 radix-select + hybrid register bitonic sort.
// [UNCHANGED from the 229 us baseline]
// ---------------------------------------------------------------------------
__global__ __launch_bounds__(256) void k3_topk(
    const float* __restrict__ tk, int* __restrict__ indices) {
  int bh = blockIdx.x;
  int t = threadIdx.x;
  int lane = t & 63;
  __shared__ unsigned us[4096];
  __shared__ unsigned hist[2048];
  __shared__ unsigned long long binlist[2048];
  __shared__ unsigned long long selk[512];
  __shared__ unsigned chunkSum[32];
  __shared__ int c1, c2, binB_s, nAbove_s, needed_s;

  {
    const float4* tk4 = (const float4*)(tk + (bh << 12));
    for (int i = t; i < 1024; i += 256) {
      float4 v = tk4[i];
      unsigned b0 = __float_as_uint(v.x), b1 = __float_as_uint(v.y);
      unsigned b2 = __float_as_uint(v.z), b3 = __float_as_uint(v.w);
      us[i * 4 + 0] = (b0 & 0x80000000u) ? ~b0 : (b0 | 0x80000000u);
      us[i * 4 + 1] = (b1 & 0x80000000u) ? ~b1 : (b1 | 0x80000000u);
      us[i * 4 + 2] = (b2 & 0x80000000u) ? ~b2 : (b2 | 0x80000000u);
      us[i * 4 + 3] = (b3 & 0x80000000u) ? ~b3 : (b3 | 0x80000000u);
    }
  }
  for (int i = t; i < 2048; i += 256) hist[i] = 0;
  if (t == 0) { c1 = 0; c2 = 0; }
  __syncthreads();

  for (int s = SINKN + t; s < SEQKV - LOCALK; s += 256)
    atomicAdd(&hist[us[s] >> 21], 1u);
  __syncthreads();

  if (t < 32) {
    unsigned sum = 0;
    for (int i = 0; i < 64; ++i) sum += hist[t * 64 + i];
    chunkSum[t] = sum;
  }
  __syncthreads();

  if (t < 64) {
    int l = t;
    unsigned x = (l < 32) ? chunkSum[l] : 0;
    unsigned sfx = x;
    for (int off = 1; off < 64; off <<= 1) {
      unsigned y = __shfl_down(sfx, off);
      if (l + off < 64) sfx += y;
    }
    unsigned above = sfx - x;
    bool hit = (l < 32) && (above < NTOP) && (above + x >= NTOP);
    unsigned long long mask = __ballot(hit);
    int C = __ffsll(mask) - 1;
    unsigned aboveC = __shfl(above, C);
    unsigned h = hist[C * 64 + l];
    unsigned sfx2 = h;
    for (int off = 1; off < 64; off <<= 1) {
      unsigned y = __shfl_down(sfx2, off);
      if (l + off < 64) sfx2 += y;
    }
    unsigned above2 = aboveC + (sfx2 - h);
    bool hit2 = (above2 < NTOP) && (above2 + h >= NTOP);
    unsigned long long mask2 = __ballot(hit2);
    int lB = __ffsll(mask2) - 1;
    if (l == lB) {
      binB_s = C * 64 + l;
      nAbove_s = (int)above2;
      needed_s = NTOP - (int)above2;
    }
  }
  __syncthreads();
  unsigned B = (unsigned)binB_s;
  int nAbove = nAbove_s, needed = needed_s;

  for (int s0 = SINKN; s0 < SEQKV - LOCALK; s0 += 256) {
    int s = s0 + t;
    bool valid = (s < SEQKV - LOCALK);
    unsigned u = valid ? us[s] : 0u;
    unsigned bin = u >> 21;
    bool win = valid && (bin > B);
    bool bnd = valid && (bin == B);
    unsigned long long mw = __ballot(win);
    unsigned long long mb = __ballot(bnd);
    int bw = 0, bb = 0;
    if (lane == 0) {
      if (mw) bw = atomicAdd(&c1, __popcll(mw));
      if (mb) bb = atomicAdd(&c2, __popcll(mb));
    }
    bw = __shfl(bw, 0);
    bb = __shfl(bb, 0);
    unsigned long long lmask = (1ULL << lane) - 1ULL;
    unsigned long long key = ((unsigned long long)u << 32) | (unsigned)(~s);
    if (win) selk[bw + __popcll(mw & lmask)] = key;
    if (bnd) {
      int pos = bb + __popcll(mb & lmask);
      if (pos < 2048) binlist[pos] = key;
    }
  }
  __syncthreads();
  int m2 = c2;
  int p2 = 1;
  while (p2 < m2) p2 <<= 1;
  for (int i = m2 + t; i < p2; i += 256) binlist[i] = 0ULL;
  __syncthreads();
  for (int k = 2; k <= p2; k <<= 1)
    for (int j = k >> 1; j > 0; j >>= 1) {
      for (int i = t; i < p2; i += 256) {
        int ixj = i ^ j;
        if (ixj > i) {
          bool desc = ((i & k) == 0);
          unsigned long long a = binlist[i], bb2 = binlist[ixj];
          if ((a < bb2) == desc) { binlist[i] = bb2; binlist[ixj] = a; }
        }
      }
      __syncthreads();
    }
  for (int i = t; i < needed; i += 256) selk[nAbove + i] = binlist[i];
  for (int i = NTOP + t; i < 512; i += 256) selk[i] = 0ULL;
  __syncthreads();

  unsigned long long e0 = selk[t], e1 = selk[t + 256];
  int i1 = t + 256;
  for (int k = 2; k <= 512; k <<= 1) {
    for (int j = k >> 1; j > 0; j >>= 1) {
      if (j == 256) {
        if (e0 < e1) { unsigned long long tmp = e0; e0 = e1; e1 = tmp; }
      } else if (j >= 64) {
        selk[t] = e0; selk[i1] = e1;
        __syncthreads();
        unsigned long long p0 = selk[t ^ j], p1 = selk[i1 ^ j];
        __syncthreads();
        bool d0 = ((t & k) == 0), l0 = ((t & j) == 0);
        e0 = (d0 == l0) ? (e0 > p0 ? e0 : p0) : (e0 < p0 ? e0 : p0);
        bool d1 = ((i1 & k) == 0), l1 = ((i1 & j) == 0);
        e1 = (d1 == l1) ? (e1 > p1 ? e1 : p1) : (e1 < p1 ? e1 : p1);
      } else {
        unsigned long long p0 = __shfl_xor(e0, j);
        unsigned long long p1 = __shfl_xor(e1, j);
        bool d0 = ((t & k) == 0), l0 = ((t & j) == 0);
        e0 = (d0 == l0) ? (e0 > p0 ? e0 : p0) : (e0 < p0 ? e0 : p0);
        bool d1 = ((i1 & k) == 0);
        e1 = (d1 == l0) ? (e1 > p1 ? e1 : p1) : (e1 < p1 ? e1 : p1);
      }
    }
  }

  if (t < SINKN) indices[bh * KSEL + t] = t;
  for (int i = t; i < LOCALK; i += 256)
    indices[bh * KSEL + SINKN + i] = (SEQKV - LOCALK) + i;
  indices[bh * KSEL + NMASK + t] = (int)(~(unsigned)(e0 & 0xFFFFFFFFu));
  if (t < NTOP - 256)
    indices[bh * KSEL + NMASK + 256 + t] = (int)(~(unsigned)(e1 & 0xFFFFFFFFu));
}

// ---------------------------------------------------------------------------
// Kernel C: fused tail (old k5+k6+k7). One block per bh, 512 threads.
//   Stage 1 (QK): 16-lane groups; 32 gathered K-row dots per round, 17 rounds.
//                 Exact scores (incl. current token) -> LDS s2s[4][520].
//   Stage 2 (stats): per-p quarter-block (128 thr): merge k2 partials, kv
//                 weight via gathered approx-score mass, softmax over 517
//                 exact scores; weights -> LDS ws2 + out_w (global output).
//   Stage 3 (V): thread=(p,d) accumulates sum_j w[p][j]*V[j][d] + the
//                 (1-kvw)*mean_v_new term; single coalesced out write.
// No atomics, no intermediate global buffers (s2_g/w_g eliminated).
// ---------------------------------------------------------------------------
__global__ __launch_bounds__(512) void kC_tail(
    const float* __restrict__ q, const float* __restrict__ key,
    const float* __restrict__ value, const float* __restrict__ lm,
    const float* __restrict__ key_cpu, const float* __restrict__ value_cpu,
    const float* __restrict__ mean_v, const float* __restrict__ scores,
    const float2* __restrict__ partials, const int* __restrict__ indices,
    float* __restrict__ out, float* __restrict__ out_w) {
  const int bh = blockIdx.x;
  const int t = threadIdx.x;
  const int wave = t >> 6, lane = t & 63;
  const int grp = lane >> 4, gl = lane & 15;

  __shared__ int sidxs[520];
  __shared__ float qv[512];
  __shared__ float s2s[4 * 520];
  __shared__ float ws2[4 * 520];
  __shared__ float redA[8], redB[8], redC[8];

  // load q (4 rows x 128) and the 516 selected indices
  qv[t] = q[((size_t)bh << 9) + t];
  for (int j = t; j < KSEL; j += 512) sidxs[j] = indices[bh * KSEL + j];
  __syncthreads();

  // ---- Stage 1: exact gathered QK^T ----
  {
    const float rsqd = 0.08838834764831845f;  // 1/sqrt(128)
    const float4* qv4 = (const float4*)qv;
    float4 qA[4], qB[4];
#pragma unroll
    for (int p = 0; p < 4; ++p) {
      qA[p] = qv4[p * 32 + gl * 2];
      qB[p] = qv4[p * 32 + gl * 2 + 1];
    }
    for (int r = 0; r < 17; ++r) {
      int j = (r << 5) + (wave << 2) + grp;  // 32 j's per round
      if (j <= KSEL) {
        int sj = (j < KSEL) ? sidxs[j] : SEQKV;
        const float* krow = (j < KSEL)
            ? key_cpu + ((((size_t)bh << 12) + sj) << 7)
            : key + ((size_t)bh << 7);
        const float4* k4 = (const float4*)krow;
        float4 kA = k4[gl * 2], kB = k4[gl * 2 + 1];
        float d0 = qA[0].x * kA.x + qA[0].y * kA.y + qA[0].z * kA.z + qA[0].w * kA.w +
                   qB[0].x * kB.x + qB[0].y * kB.y + qB[0].z * kB.z + qB[0].w * kB.w;
        float d1 = qA[1].x * kA.x + qA[1].y * kA.y + qA[1].z * kA.z + qA[1].w * kA.w +
                   qB[1].x * kB.x + qB[1].y * kB.y + qB[1].z * kB.z + qB[1].w * kB.w;
        float d2 = qA[2].x * kA.x + qA[2].y * kA.y + qA[2].z * kA.z + qA[2].w * kA.w +
                   qB[2].x * kB.x + qB[2].y * kB.y + qB[2].z * kB.z + qB[2].w * kB.w;
        float d3 = qA[3].x * kA.x + qA[3].y * kA.y + qA[3].z * kA.z + qA[3].w * kA.w +
                   qB[3].x * kB.x + qB[3].y * kB.y + qB[3].z * kB.z + qB[3].w * kB.w;
        for (int off = 8; off > 0; off >>= 1) {
          d0 += __shfl_down(d0, off);
          d1 += __shfl_down(d1, off);
          d2 += __shfl_down(d2, off);
          d3 += __shfl_down(d3, off);
        }
        if (gl == 0) {
          size_t lmb = (size_t)(bh * 4) * SEQN + sj;
          s2s[0 * 520 + j] = d0 * rsqd + lm[lmb + 0 * SEQN];
          s2s[1 * 520 + j] = d1 * rsqd + lm[lmb + 1 * SEQN];
          s2s[2 * 520 + j] = d2 * rsqd + lm[lmb + 2 * SEQN];
          s2s[3 * 520 + j] = d3 * rsqd + lm[lmb + 3 * SEQN];
        }
      }
    }
  }
  __syncthreads();

  // ---- Stage 2: stats + softmax (quarter-block per p) ----
  const int p = t >> 7, tt = t & 127;
  const int qw = tt >> 6;  // wave within quarter
  const int bhp = bh * 4 + p;
  float kvw;
  {
    const float* srow = scores + (size_t)bhp * SSTR;
    float cur = srow[SEQKV];

    // merge the 16 per-chunk partials (uniform within quarter)
    float m = cur, sumexp;
    {
      float2 pc[NCHUNK];
#pragma unroll
      for (int c = 0; c < NCHUNK; ++c) {
        pc[c] = partials[(size_t)bhp * NCHUNK + c];
        m = fmaxf(m, pc[c].x);
      }
      float s = expf(cur - m);
#pragma unroll
      for (int c = 0; c < NCHUNK; ++c) s += pc[c].y * expf(pc[c].x - m);
      sumexp = s;
    }

    // selected approx-score mass (gather over 516 positions)
    float ss = 0.f;
    for (int j = tt; j < KSEL; j += 128) ss += expf(srow[sidxs[j]] - m);
    for (int off = 32; off > 0; off >>= 1) ss += __shfl_down(ss, off);
    if (lane == 0) redA[p * 2 + qw] = ss;
    __syncthreads();
    float sstot = redA[p * 2] + redA[p * 2 + 1];
    kvw = (sstot + expf(cur - m)) / sumexp;

    // softmax over the 517 exact scores (in LDS)
    float mx = -INFINITY;
    for (int j = tt; j < KSEL + 1; j += 128) mx = fmaxf(mx, s2s[p * 520 + j]);
    for (int off = 32; off > 0; off >>= 1) mx = fmaxf(mx, __shfl_down(mx, off));
    if (lane == 0) redB[p * 2 + qw] = mx;
    __syncthreads();
    float m2 = fmaxf(redB[p * 2], redB[p * 2 + 1]);
    float se = 0.f;
    for (int j = tt; j < KSEL + 1; j += 128) se += expf(s2s[p * 520 + j] - m2);
    for (int off = 32; off > 0; off >>= 1) se += __shfl_down(se, off);
    if (lane == 0) redC[p * 2 + qw] = se;
    __syncthreads();
    float inv = kvw / (redC[p * 2] + redC[p * 2 + 1]);

    for (int j = tt; j < KSEL + 1; j += 128) {
      float w = expf(s2s[p * 520 + j] - m2) * inv;
      ws2[p * 520 + j] = w;
      out_w[(size_t)bhp * (KSEL + 1) + j] = w;
    }
  }
  __syncthreads();

  // ---- Stage 3: out[p][d] = sum_j w*V + (1-kvw)*mean_v_new ----
  {
    const int d = tt;  // thread=(p,d)
    float vcur = value[((size_t)bh << 7) + d];
    float mvn = (mean_v[((size_t)bh << 7) + d] * 4096.f + vcur) / 4097.f;
    float a0 = (1.f - kvw) * mvn, a1 = 0.f, a2 = 0.f, a3 = 0.f;
    const float* vbase = value_cpu + ((size_t)bh << 19);  // bh*4096*128
    for (int j = 0; j < KSEL; j += 4) {  // 516 = 4*129 exactly
      int s0 = sidxs[j], s1 = sidxs[j + 1], s2i = sidxs[j + 2], s3 = sidxs[j + 3];
      a0 += ws2[p * 520 + j] * vbase[((size_t)s0 << 7) + d];
      a1 += ws2[p * 520 + j + 1] * vbase[((size_t)s1 << 7) + d];
      a2 += ws2[p * 520 + j + 2] * vbase[((size_t)s2i << 7) + d];
      a3 += ws2[p * 520 + j + 3] * vbase[((size_t)s3 << 7) + d];
    }
    a0 += ws2[p * 520 + KSEL] * vcur;  // current token
    out[((size_t)bhp << 7) + d] = (a0 + a1) + (a2 + a3);
  }
}

// ---------------------------------------------------------------------------
extern "C" void kernel_launch(void* const* d_in, const int* in_sizes, int n_in,
                              void* d_out, int out_size, void* d_ws, size_t ws_size,
                              hipStream_t stream) {
  const float* query     = (const float*)d_in[0];
  const float* key       = (const float*)d_in[1];
  const float* value     = (const float*)d_in[2];
  const float* logmask   = (const float*)d_in[3];
  const float* key_cpu   = (const float*)d_in[4];
  const float* value_cpu = (const float*)d_in[5];
  const float* s_key_cpu = (const float*)d_in[6];
  const float* mean_v    = (const float*)d_in[7];

  float* out   = (float*)d_out;       // (4,32,1,128) = 16384 floats
  float* out_w = out + 16384;         // (4,32,1,517) = 66176 floats

  char* ws = (char*)d_ws;
  int*    indices  = (int*)(ws + 20480);          // 66048 B
  float*  scores   = (float*)(ws + 86528);        // 128*4100*4 = 2099200 B
  float*  tk       = (float*)(ws + 2185728);      // 524288 B
  float2* partials = (float2*)(ws + 3242496);     // 128*16*8 = 16384 B

  hipLaunchKernelGGL(k2_scores, dim3(NCHUNK, NBH), dim3(256), 0, stream,
                     query, key, s_key_cpu, logmask, scores, tk, partials);
  hipLaunchKernelGGL(k3_topk, dim3(NBH), dim3(256), 0, stream,
                     tk, indices);
  hipLaunchKernelGGL(kC_tail, dim3(NBH), dim3(512), 0, stream,
                     query, key, value, logmask, key_cpu, value_cpu,
                     mean_v, scores, partials, indices, out, out_w);
}

// Round 4
// 254.206 us; speedup vs baseline: 1.6726x; 1.0154x over previous
//
#include <hip/hip_runtime.h>
#include <math.h>

// Problem constants
#define NBH 32     // B*KVH = 4*8
#define HPKN 4
#define DN 128
#define SEQKV 4096
#define SEQN 4097
#define SSTR 4100  // padded score-row stride
#define RANKN 32
#define KSEL 516   // K + SINK = 512 + 4
#define SINKN 4
#define LOCALK 128
#define NMASK 132  // SINKN + LOCALK
#define NTOP 384   // KSEL - NMASK
#define NCHUNK 16  // k2 position-chunks per bh
#define NCH2 8     // tail chunk blocks per bh
#define NJC 65     // selected-j's per tail block (8*65=520 >= 517)

// ---------------------------------------------------------------------------
// Kernel 2: approx scores. grid (16, 32 bh), block 256.
// [UNCHANGED from the 229us baseline, plus: block x==0 zeroes ctrB[bh]]
// ---------------------------------------------------------------------------
__global__ __launch_bounds__(256) void k2_scores(
    const float* __restrict__ q, const float* __restrict__ key,
    const float* __restrict__ skey, const float* __restrict__ lm,
    float* __restrict__ scores, float* __restrict__ tk,
    float2* __restrict__ partials, int* __restrict__ ctrB) {
  int bh = blockIdx.y;
  int s0 = blockIdx.x << 8;
  int t = threadIdx.x;
  int wave = t >> 6, lane = t & 63;
  __shared__ float qv[4][128];
  __shared__ float absq[128];
  __shared__ int sel[RANKN];
  __shared__ float qp[4][RANKN];
  __shared__ float wred[4][4];

  if (blockIdx.x == 0 && t == 0) ctrB[bh] = 0;  // init tail merge counter

  {
    float v0 = q[(size_t)bh * 512 + t];
    float v1 = q[(size_t)bh * 512 + 256 + t];
    qv[t >> 7][t & 127] = v0;
    qv[2 + (t >> 7)][t & 127] = v1;
  }
  __syncthreads();
  if (t < 128)
    absq[t] = fabsf(qv[0][t]) + fabsf(qv[1][t]) + fabsf(qv[2][t]) + fabsf(qv[3][t]);
  __syncthreads();
  if (t < 128) {
    float a = absq[t];
    int rank = 0;
    for (int e = 0; e < 128; ++e) {
      float ae = absq[e];
      rank += (ae > a) || (ae == a && e < t);
    }
    if (rank < RANKN) sel[rank] = t;
  }
  __syncthreads();
  {
    float fa = fabsf(qv[wave][lane]) + fabsf(qv[wave][lane + 64]);
    for (int off = 32; off > 0; off >>= 1) fa += __shfl_down(fa, off);
    float full = __shfl(fa, 0);
    float qsel = (lane < RANKN) ? qv[wave][sel[lane]] : 0.f;
    float sv = fabsf(qsel);
    for (int off = 32; off > 0; off >>= 1) sv += __shfl_down(sv, off);
    float selsum = __shfl(sv, 0);
    float scale = sqrtf(selsum / full * 128.f);
    if (lane < RANKN) qp[wave][lane] = qsel / scale;
  }
  __syncthreads();

  if (blockIdx.x == 0) {
    float kv = (lane < RANKN) ? key[bh * 128 + sel[lane]] : 0.f;
    float pr = (lane < RANKN) ? qp[wave][lane] * kv : 0.f;
    for (int off = 32; off > 0; off >>= 1) pr += __shfl_down(pr, off);
    if (lane == 0)
      scores[(size_t)(bh * 4 + wave) * SSTR + SEQKV] =
          pr + lm[(size_t)(bh * 4 + wave) * SEQN + SEQKV];
  }

  const float* kb = skey + (size_t)bh * 128 * 4096;
  float a0 = 0, a1 = 0, a2 = 0, a3 = 0;
#pragma unroll 8
  for (int r = 0; r < RANKN; ++r) {
    float k0 = kb[((size_t)sel[r] << 12) + s0 + t];
    a0 += qp[0][r] * k0;
    a1 += qp[1][r] * k0;
    a2 += qp[2][r] * k0;
    a3 += qp[3][r] * k0;
  }
  float sc[4];
  {
    int s = s0 + t;
    sc[0] = a0 + lm[(size_t)(bh * 4 + 0) * SEQN + s];
    sc[1] = a1 + lm[(size_t)(bh * 4 + 1) * SEQN + s];
    sc[2] = a2 + lm[(size_t)(bh * 4 + 2) * SEQN + s];
    sc[3] = a3 + lm[(size_t)(bh * 4 + 3) * SEQN + s];
    float sum = sc[0] + sc[1] + sc[2] + sc[3];
#pragma unroll
    for (int p = 0; p < 4; ++p)
      scores[(size_t)(bh * 4 + p) * SSTR + s] = sc[p];
    tk[(bh << 12) + s] = sum;
  }

#pragma unroll
  for (int p = 0; p < 4; ++p) {
    float mx = sc[p];
    for (int off = 32; off > 0; off >>= 1) mx = fmaxf(mx, __shfl_down(mx, off));
    if (lane == 0) wred[wave][p] = mx;
  }
  __syncthreads();
  float bm[4];
#pragma unroll
  for (int p = 0; p < 4; ++p)
    bm[p] = fmaxf(fmaxf(wred[0][p], wred[1][p]), fmaxf(wred[2][p], wred[3][p]));
  __syncthreads();
#pragma unroll
  for (int p = 0; p < 4; ++p) {
    float e = expf(sc[p] - bm[p]);
    for (int off = 32; off > 0; off >>= 1) e += __shfl_down(e, off);
    if (lane == 0) wred[wave][p] = e;
  }
  __syncthreads();
  if (t < 4) {
    float s = wred[0][t] + wred[1][t] + wred[2][t] + wred[3][t];
    partials[(size_t)(bh * 4 + t) * NCHUNK + blockIdx.x] = make_float2(bm[t], s);
  }
}

// ---------------------------------------------------------------------------
// Kernel 3: top-384 radix-select + hybrid bitonic. [UNCHANGED, known-good]
// ---------------------------------------------------------------------------
__global__ __launch_bounds__(256) void k3_topk(
    const float* __restrict__ tk, int* __restrict__ indices) {
  int bh = blockIdx.x;
  int t = threadIdx.x;
  int lane = t & 63;
  __shared__ unsigned us[4096];
  __shared__ unsigned hist[2048];
  __shared__ unsigned long long binlist[2048];
  __shared__ unsigned long long selk[512];
  __shared__ unsigned chunkSum[32];
  __shared__ int c1, c2, binB_s, nAbove_s, needed_s;

  {
    const float4* tk4 = (const float4*)(tk + (bh << 12));
    for (int i = t; i < 1024; i += 256) {
      float4 v = tk4[i];
      unsigned b0 = __float_as_uint(v.x), b1 = __float_as_uint(v.y);
      unsigned b2 = __float_as_uint(v.z), b3 = __float_as_uint(v.w);
      us[i * 4 + 0] = (b0 & 0x80000000u) ? ~b0 : (b0 | 0x80000000u);
      us[i * 4 + 1] = (b1 & 0x80000000u) ? ~b1 : (b1 | 0x80000000u);
      us[i * 4 + 2] = (b2 & 0x80000000u) ? ~b2 : (b2 | 0x80000000u);
      us[i * 4 + 3] = (b3 & 0x80000000u) ? ~b3 : (b3 | 0x80000000u);
    }
  }
  for (int i = t; i < 2048; i += 256) hist[i] = 0;
  if (t == 0) { c1 = 0; c2 = 0; }
  __syncthreads();

  for (int s = SINKN + t; s < SEQKV - LOCALK; s += 256)
    atomicAdd(&hist[us[s] >> 21], 1u);
  __syncthreads();

  if (t < 32) {
    unsigned sum = 0;
    for (int i = 0; i < 64; ++i) sum += hist[t * 64 + i];
    chunkSum[t] = sum;
  }
  __syncthreads();

  if (t < 64) {
    int l = t;
    unsigned x = (l < 32) ? chunkSum[l] : 0;
    unsigned sfx = x;
    for (int off = 1; off < 64; off <<= 1) {
      unsigned y = __shfl_down(sfx, off);
      if (l + off < 64) sfx += y;
    }
    unsigned above = sfx - x;
    bool hit = (l < 32) && (above < NTOP) && (above + x >= NTOP);
    unsigned long long mask = __ballot(hit);
    int C = __ffsll(mask) - 1;
    unsigned aboveC = __shfl(above, C);
    unsigned h = hist[C * 64 + l];
    unsigned sfx2 = h;
    for (int off = 1; off < 64; off <<= 1) {
      unsigned y = __shfl_down(sfx2, off);
      if (l + off < 64) sfx2 += y;
    }
    unsigned above2 = aboveC + (sfx2 - h);
    bool hit2 = (above2 < NTOP) && (above2 + h >= NTOP);
    unsigned long long mask2 = __ballot(hit2);
    int lB = __ffsll(mask2) - 1;
    if (l == lB) {
      binB_s = C * 64 + l;
      nAbove_s = (int)above2;
      needed_s = NTOP - (int)above2;
    }
  }
  __syncthreads();
  unsigned B = (unsigned)binB_s;
  int nAbove = nAbove_s, needed = needed_s;

  for (int s0 = SINKN; s0 < SEQKV - LOCALK; s0 += 256) {
    int s = s0 + t;
    bool valid = (s < SEQKV - LOCALK);
    unsigned u = valid ? us[s] : 0u;
    unsigned bin = u >> 21;
    bool win = valid && (bin > B);
    bool bnd = valid && (bin == B);
    unsigned long long mw = __ballot(win);
    unsigned long long mb = __ballot(bnd);
    int bw = 0, bb = 0;
    if (lane == 0) {
      if (mw) bw = atomicAdd(&c1, __popcll(mw));
      if (mb) bb = atomicAdd(&c2, __popcll(mb));
    }
    bw = __shfl(bw, 0);
    bb = __shfl(bb, 0);
    unsigned long long lmask = (1ULL << lane) - 1ULL;
    unsigned long long key = ((unsigned long long)u << 32) | (unsigned)(~s);
    if (win) selk[bw + __popcll(mw & lmask)] = key;
    if (bnd) {
      int pos = bb + __popcll(mb & lmask);
      if (pos < 2048) binlist[pos] = key;
    }
  }
  __syncthreads();
  int m2 = c2;
  int p2 = 1;
  while (p2 < m2) p2 <<= 1;
  for (int i = m2 + t; i < p2; i += 256) binlist[i] = 0ULL;
  __syncthreads();
  for (int k = 2; k <= p2; k <<= 1)
    for (int j = k >> 1; j > 0; j >>= 1) {
      for (int i = t; i < p2; i += 256) {
        int ixj = i ^ j;
        if (ixj > i) {
          bool desc = ((i & k) == 0);
          unsigned long long a = binlist[i], bb2 = binlist[ixj];
          if ((a < bb2) == desc) { binlist[i] = bb2; binlist[ixj] = a; }
        }
      }
      __syncthreads();
    }
  for (int i = t; i < needed; i += 256) selk[nAbove + i] = binlist[i];
  for (int i = NTOP + t; i < 512; i += 256) selk[i] = 0ULL;
  __syncthreads();

  unsigned long long e0 = selk[t], e1 = selk[t + 256];
  int i1 = t + 256;
  for (int k = 2; k <= 512; k <<= 1) {
    for (int j = k >> 1; j > 0; j >>= 1) {
      if (j == 256) {
        if (e0 < e1) { unsigned long long tmp = e0; e0 = e1; e1 = tmp; }
      } else if (j >= 64) {
        selk[t] = e0; selk[i1] = e1;
        __syncthreads();
        unsigned long long p0 = selk[t ^ j], p1 = selk[i1 ^ j];
        __syncthreads();
        bool d0 = ((t & k) == 0), l0 = ((t & j) == 0);
        e0 = (d0 == l0) ? (e0 > p0 ? e0 : p0) : (e0 < p0 ? e0 : p0);
        bool d1 = ((i1 & k) == 0), l1 = ((i1 & j) == 0);
        e1 = (d1 == l1) ? (e1 > p1 ? e1 : p1) : (e1 < p1 ? e1 : p1);
      } else {
        unsigned long long p0 = __shfl_xor(e0, j);
        unsigned long long p1 = __shfl_xor(e1, j);
        bool d0 = ((t & k) == 0), l0 = ((t & j) == 0);
        e0 = (d0 == l0) ? (e0 > p0 ? e0 : p0) : (e0 < p0 ? e0 : p0);
        bool d1 = ((i1 & k) == 0);
        e1 = (d1 == l0) ? (e1 > p1 ? e1 : p1) : (e1 < p1 ? e1 : p1);
      }
    }
  }

  if (t < SINKN) indices[bh * KSEL + t] = t;
  for (int i = t; i < LOCALK; i += 256)
    indices[bh * KSEL + SINKN + i] = (SEQKV - LOCALK) + i;
  indices[bh * KSEL + NMASK + t] = (int)(~(unsigned)(e0 & 0xFFFFFFFFu));
  if (t < NTOP - 256)
    indices[bh * KSEL + NMASK + 256 + t] = (int)(~(unsigned)(e1 & 0xFFFFFFFFu));
}

// ---------------------------------------------------------------------------
// Kernel B: wide fused tail. grid (8 chunks, 32 bh), block 256.
// Per block: gathered QK^T for its 65 j's -> s2 (LDS + s2_g global),
// per-chunk softmax partials (mloc, sumloc) and partial V-accum
// pv[d] = sum_j exp(s2-mloc)*V[j][d].  Last block per bh (counter, fenced)
// merges: flash-rescale, kv_weight, writes out + out_w.
// Workspace footprint kept <= 3,258,880 B (proven): pv aliases tk.
// ---------------------------------------------------------------------------
__global__ __launch_bounds__(256) void kB_tail(
    const float* __restrict__ q, const float* __restrict__ key,
    const float* __restrict__ value, const float* __restrict__ lm,
    const float* __restrict__ key_cpu, const float* __restrict__ value_cpu,
    const float* __restrict__ mean_v, const float* __restrict__ scores,
    const float2* __restrict__ partials, const int* __restrict__ indices,
    float* __restrict__ pv, float2* __restrict__ pms,
    float* __restrict__ s2_g, int* __restrict__ ctrB,
    float* __restrict__ out, float* __restrict__ out_w) {
  const int bh = blockIdx.y;
  const int c = blockIdx.x;
  const int t = threadIdx.x;
  const int wave = t >> 6, lane = t & 63;

  __shared__ float qv[512];
  __shared__ int sidx[NJC];
  __shared__ float s2[4][NJC];
  __shared__ float we[4][NJC];
  __shared__ float mred[4], sred[4];
  __shared__ int sidxAll[KSEL];
  __shared__ float ef[NCH2 * 4];
  __shared__ float mm[4], sg[4], kvws[4];
  __shared__ int lastFlag;

  const int j0 = c * NJC;
  const int nj = min(NJC, KSEL + 1 - j0);

  qv[t] = q[((size_t)bh << 9) + t];
  qv[t + 256] = q[((size_t)bh << 9) + t + 256];
  if (t < nj) {
    int j = j0 + t;
    sidx[t] = (j < KSEL) ? indices[bh * KSEL + j] : -1;
  }
  __syncthreads();

  // ---- gathered QK^T: 16 groups of 16 lanes, 5 rounds ----
  {
    const float rsqd = 0.08838834764831845f;  // 1/sqrt(128)
    const int grp = t >> 4, gl = t & 15;
    const float4* qv4 = (const float4*)qv;
    float4 qA[4], qB[4];
#pragma unroll
    for (int p = 0; p < 4; ++p) {
      qA[p] = qv4[p * 32 + gl * 2];
      qB[p] = qv4[p * 32 + gl * 2 + 1];
    }
#pragma unroll
    for (int r = 0; r < 5; ++r) {
      int jl = grp + (r << 4);
      if (jl < nj) {
        int sj = sidx[jl];
        const float* krow = (sj >= 0)
            ? key_cpu + ((((size_t)bh << 12) + sj) << 7)
            : key + ((size_t)bh << 7);
        const float4* k4 = (const float4*)krow;
        float4 kA = k4[gl * 2], kB4 = k4[gl * 2 + 1];
        float d0 = qA[0].x * kA.x + qA[0].y * kA.y + qA[0].z * kA.z + qA[0].w * kA.w +
                   qB[0].x * kB4.x + qB[0].y * kB4.y + qB[0].z * kB4.z + qB[0].w * kB4.w;
        float d1 = qA[1].x * kA.x + qA[1].y * kA.y + qA[1].z * kA.z + qA[1].w * kA.w +
                   qB[1].x * kB4.x + qB[1].y * kB4.y + qB[1].z * kB4.z + qB[1].w * kB4.w;
        float d2 = qA[2].x * kA.x + qA[2].y * kA.y + qA[2].z * kA.z + qA[2].w * kA.w +
                   qB[2].x * kB4.x + qB[2].y * kB4.y + qB[2].z * kB4.z + qB[2].w * kB4.w;
        float d3 = qA[3].x * kA.x + qA[3].y * kA.y + qA[3].z * kA.z + qA[3].w * kA.w +
                   qB[3].x * kB4.x + qB[3].y * kB4.y + qB[3].z * kB4.z + qB[3].w * kB4.w;
        for (int off = 8; off > 0; off >>= 1) {
          d0 += __shfl_down(d0, off);
          d1 += __shfl_down(d1, off);
          d2 += __shfl_down(d2, off);
          d3 += __shfl_down(d3, off);
        }
        if (gl == 0) {
          int s = (sj >= 0) ? sj : SEQKV;
          size_t lmb = (size_t)(bh * 4) * SEQN + s;
          s2[0][jl] = d0 * rsqd + lm[lmb + 0 * SEQN];
          s2[1][jl] = d1 * rsqd + lm[lmb + 1 * SEQN];
          s2[2][jl] = d2 * rsqd + lm[lmb + 2 * SEQN];
          s2[3][jl] = d3 * rsqd + lm[lmb + 3 * SEQN];
        }
      }
    }
  }
  __syncthreads();

  // ---- per-p chunk stats: mloc, sumloc, we = exp(s2-mloc) (wave==p) ----
  {
    const int p = wave;
    float va = (lane < nj) ? s2[p][lane] : -INFINITY;
    float vb = (lane + 64 < nj) ? s2[p][lane + 64] : -INFINITY;
    float mx = fmaxf(va, vb);
    for (int off = 32; off > 0; off >>= 1) mx = fmaxf(mx, __shfl_down(mx, off));
    mx = __shfl(mx, 0);
    float ea = (lane < nj) ? expf(va - mx) : 0.f;
    float eb = (lane + 64 < nj) ? expf(vb - mx) : 0.f;
    if (lane < nj) we[p][lane] = ea;
    if (lane + 64 < nj) we[p][lane + 64] = eb;
    float su = ea + eb;
    for (int off = 32; off > 0; off >>= 1) su += __shfl_down(su, off);
    if (lane == 0) { mred[p] = mx; sred[p] = su; }
  }
  __syncthreads();

  // ---- partial V-accum: thread=(pp,d) handles p=pp and p=pp+2 ----
  {
    const int d = t & 127, pp = t >> 7;
    float a0 = 0.f, a1 = 0.f;
    for (int jl = 0; jl < nj; ++jl) {
      int sj = sidx[jl];
      const float* vrow = (sj >= 0)
          ? value_cpu + ((((size_t)bh << 12) + sj) << 7)
          : value + ((size_t)bh << 7);
      float v = vrow[d];
      a0 += we[pp][jl] * v;
      a1 += we[pp + 2][jl] * v;
    }
    int base = (bh * NCH2 + c) * 4;
    pv[(size_t)(base + pp) * 128 + d] = a0;
    pv[(size_t)(base + pp + 2) * 128 + d] = a1;
    if (t < 4) pms[base + t] = make_float2(mred[t], sred[t]);
  }
  // s2 rows to global for the merge block (out_w needs per-j scores)
  if (t < nj) {
#pragma unroll
    for (int p = 0; p < 4; ++p)
      s2_g[(size_t)(bh * 4 + p) * 520 + j0 + t] = s2[p][t];
  }

  __threadfence();
  __syncthreads();
  if (t == 0) lastFlag = (atomicAdd(&ctrB[bh], 1) == NCH2 - 1);
  __syncthreads();
  if (!lastFlag) return;
  __threadfence();

  // ======================= merge (one block per bh) ========================
  for (int jj = t; jj < KSEL; jj += 256) sidxAll[jj] = indices[bh * KSEL + jj];
  __syncthreads();

  {
    const int p = wave;
    const int bhp = bh * 4 + p;
    // flash-merge of 8 chunk partials
    float2 mp = (lane < NCH2) ? pms[(bh * NCH2 + lane) * 4 + p]
                              : make_float2(-INFINITY, 0.f);
    float m2 = mp.x;
    for (int off = 32; off > 0; off >>= 1) m2 = fmaxf(m2, __shfl_down(m2, off));
    m2 = __shfl(m2, 0);
    float sig = (lane < NCH2) ? mp.y * expf(mp.x - m2) : 0.f;
    for (int off = 32; off > 0; off >>= 1) sig += __shfl_down(sig, off);
    sig = __shfl(sig, 0);
    if (lane < NCH2) ef[lane * 4 + p] = expf(mp.x - m2);

    // kv_weight from approx-score stats (k2 partials + gathered mass)
    const float* srow = scores + (size_t)bhp * SSTR;
    float cur = srow[SEQKV];
    float2 pc = (lane < NCHUNK) ? partials[(size_t)bhp * NCHUNK + lane]
                                : make_float2(-INFINITY, 0.f);
    float mA = fmaxf(pc.x, cur);
    for (int off = 32; off > 0; off >>= 1) mA = fmaxf(mA, __shfl_down(mA, off));
    mA = __shfl(mA, 0);
    float sA = (lane < NCHUNK) ? pc.y * expf(pc.x - mA) : 0.f;
    for (int off = 32; off > 0; off >>= 1) sA += __shfl_down(sA, off);
    sA = __shfl(sA, 0) + expf(cur - mA);
    float selm = 0.f;
    for (int jj = lane; jj < KSEL; jj += 64) selm += expf(srow[sidxAll[jj]] - mA);
    for (int off = 32; off > 0; off >>= 1) selm += __shfl_down(selm, off);
    selm = __shfl(selm, 0);
    float kvw = (selm + expf(cur - mA)) / sA;
    if (lane == 0) { mm[p] = m2; sg[p] = sig; kvws[p] = kvw; }
  }
  __syncthreads();

  // out_w: w[j] = exp(s2-m2)/sig * kvw
#pragma unroll
  for (int p = 0; p < 4; ++p) {
    float scl = kvws[p] / sg[p], mmp = mm[p];
    const float* s2r = s2_g + (size_t)(bh * 4 + p) * 520;
    for (int jj = t; jj < KSEL + 1; jj += 256)
      out_w[(size_t)(bh * 4 + p) * (KSEL + 1) + jj] = expf(s2r[jj] - mmp) * scl;
  }

  // out: merge pv with rescale factors + (1-kvw)*mean_v_new
  {
    const int d = t & 127, pp = t >> 7;
    float vcur = value[((size_t)bh << 7) + d];
    float mvn = (mean_v[((size_t)bh << 7) + d] * 4096.f + vcur) / 4097.f;
#pragma unroll
    for (int pi = 0; pi < 2; ++pi) {
      int p = pp + pi * 2;
      float acc = 0.f;
#pragma unroll
      for (int c2 = 0; c2 < NCH2; ++c2)
        acc += pv[(size_t)((bh * NCH2 + c2) * 4 + p) * 128 + d] * ef[c2 * 4 + p];
      out[(size_t)(bh * 4 + p) * 128 + d] =
          acc * kvws[p] / sg[p] + (1.f - kvws[p]) * mvn;
    }
  }
}

// ---------------------------------------------------------------------------
// Workspace layout (max offset 3,258,880 B == proven baseline footprint):
//   ctrB     ws+0        128 B
//   pms      ws+128      8192 B   (32*8*4 float2)
//   indices  ws+20480    66048 B
//   scores   ws+86528    2099200 B
//   tk       ws+2185728  524288 B  (dead after k3)
//   pv       ws+2185728  524288 B  (aliases tk; kB runs after k3)
//   s2_g     ws+2710016  266240 B
//   partials ws+3242496  16384 B
// ---------------------------------------------------------------------------
extern "C" void kernel_launch(void* const* d_in, const int* in_sizes, int n_in,
                              void* d_out, int out_size, void* d_ws, size_t ws_size,
                              hipStream_t stream) {
  const float* query     = (const float*)d_in[0];
  const float* key       = (const float*)d_in[1];
  const float* value     = (const float*)d_in[2];
  const float* logmask   = (const float*)d_in[3];
  const float* key_cpu   = (const float*)d_in[4];
  const float* value_cpu = (const float*)d_in[5];
  const float* s_key_cpu = (const float*)d_in[6];
  const float* mean_v    = (const float*)d_in[7];

  float* out   = (float*)d_out;       // (4,32,1,128) = 16384 floats
  float* out_w = out + 16384;         // (4,32,1,517) = 66176 floats

  char* ws = (char*)d_ws;
  int*    ctrB     = (int*)(ws + 0);
  float2* pms      = (float2*)(ws + 128);
  int*    indices  = (int*)(ws + 20480);
  float*  scores   = (float*)(ws + 86528);
  float*  tk       = (float*)(ws + 2185728);
  float*  pv       = (float*)(ws + 2185728);   // aliases tk (dead after k3)
  float*  s2_g     = (float*)(ws + 2710016);
  float2* partials = (float2*)(ws + 3242496);

  hipLaunchKernelGGL(k2_scores, dim3(NCHUNK, NBH), dim3(256), 0, stream,
                     query, key, s_key_cpu, logmask, scores, tk, partials, ctrB);
  hipLaunchKernelGGL(k3_topk, dim3(NBH), dim3(256), 0, stream,
                     tk, indices);
  hipLaunchKernelGGL(kB_tail, dim3(NCH2, NBH), dim3(256), 0, stream,
                     query, key, value, logmask, key_cpu, value_cpu,
                     mean_v, scores, partials, indices,
                     pv, pms, s2_g, ctrB, out, out_w);
}

// Round 6
// 224.831 us; speedup vs baseline: 1.8911x; 1.1307x over previous
//
#include <hip/hip_runtime.h>
#include <math.h>

// Problem constants
#define NBH 32     // B*KVH = 4*8
#define HPKN 4
#define DN 128
#define SEQKV 4096
#define SEQN 4097
#define SSTR 4100  // padded score-row stride (keeps float4 alignment per row)
#define RANKN 32
#define KSEL 516   // K + SINK = 512 + 4
#define SINKN 4
#define LOCALK 128 // masked-local region starts at SEQKV - LOCALK = 3968
#define NMASK 132  // SINKN + LOCALK
#define NTOP 384   // KSEL - NMASK
#define NCHUNK 16  // k2 position-chunks per bh

// ---------------------------------------------------------------------------
// Kernel 2: approx scores. grid (16, 32 bh), block 256.
// [byte-identical to the 229us baseline]
// ---------------------------------------------------------------------------
__global__ __launch_bounds__(256) void k2_scores(
    const float* __restrict__ q, const float* __restrict__ key,
    const float* __restrict__ skey, const float* __restrict__ lm,
    float* __restrict__ scores, float* __restrict__ tk,
    float2* __restrict__ partials) {
  int bh = blockIdx.y;
  int s0 = blockIdx.x << 8;
  int t = threadIdx.x;
  int wave = t >> 6, lane = t & 63;
  __shared__ float qv[4][128];
  __shared__ float absq[128];
  __shared__ int sel[RANKN];
  __shared__ float qp[4][RANKN];
  __shared__ float wred[4][4];

  {
    float v0 = q[(size_t)bh * 512 + t];
    float v1 = q[(size_t)bh * 512 + 256 + t];
    qv[t >> 7][t & 127] = v0;
    qv[2 + (t >> 7)][t & 127] = v1;
  }
  __syncthreads();
  if (t < 128)
    absq[t] = fabsf(qv[0][t]) + fabsf(qv[1][t]) + fabsf(qv[2][t]) + fabsf(qv[3][t]);
  __syncthreads();
  if (t < 128) {
    float a = absq[t];
    int rank = 0;
    for (int e = 0; e < 128; ++e) {
      float ae = absq[e];
      rank += (ae > a) || (ae == a && e < t);
    }
    if (rank < RANKN) sel[rank] = t;
  }
  __syncthreads();
  {
    float fa = fabsf(qv[wave][lane]) + fabsf(qv[wave][lane + 64]);
    for (int off = 32; off > 0; off >>= 1) fa += __shfl_down(fa, off);
    float full = __shfl(fa, 0);
    float qsel = (lane < RANKN) ? qv[wave][sel[lane]] : 0.f;
    float sv = fabsf(qsel);
    for (int off = 32; off > 0; off >>= 1) sv += __shfl_down(sv, off);
    float selsum = __shfl(sv, 0);
    float scale = sqrtf(selsum / full * 128.f);
    if (lane < RANKN) qp[wave][lane] = qsel / scale;
  }
  __syncthreads();

  if (blockIdx.x == 0) {
    float kv = (lane < RANKN) ? key[bh * 128 + sel[lane]] : 0.f;
    float pr = (lane < RANKN) ? qp[wave][lane] * kv : 0.f;
    for (int off = 32; off > 0; off >>= 1) pr += __shfl_down(pr, off);
    if (lane == 0)
      scores[(size_t)(bh * 4 + wave) * SSTR + SEQKV] =
          pr + lm[(size_t)(bh * 4 + wave) * SEQN + SEQKV];
  }

  const float* kb = skey + (size_t)bh * 128 * 4096;
  float a0 = 0, a1 = 0, a2 = 0, a3 = 0;
#pragma unroll 8
  for (int r = 0; r < RANKN; ++r) {
    float k0 = kb[((size_t)sel[r] << 12) + s0 + t];
    a0 += qp[0][r] * k0;
    a1 += qp[1][r] * k0;
    a2 += qp[2][r] * k0;
    a3 += qp[3][r] * k0;
  }
  float sc[4];
  {
    int s = s0 + t;
    sc[0] = a0 + lm[(size_t)(bh * 4 + 0) * SEQN + s];
    sc[1] = a1 + lm[(size_t)(bh * 4 + 1) * SEQN + s];
    sc[2] = a2 + lm[(size_t)(bh * 4 + 2) * SEQN + s];
    sc[3] = a3 + lm[(size_t)(bh * 4 + 3) * SEQN + s];
    float sum = sc[0] + sc[1] + sc[2] + sc[3];
#pragma unroll
    for (int p = 0; p < 4; ++p)
      scores[(size_t)(bh * 4 + p) * SSTR + s] = sc[p];
    tk[(bh << 12) + s] = sum;
  }

#pragma unroll
  for (int p = 0; p < 4; ++p) {
    float mx = sc[p];
    for (int off = 32; off > 0; off >>= 1) mx = fmaxf(mx, __shfl_down(mx, off));
    if (lane == 0) wred[wave][p] = mx;
  }
  __syncthreads();
  float bm[4];
#pragma unroll
  for (int p = 0; p < 4; ++p)
    bm[p] = fmaxf(fmaxf(wred[0][p], wred[1][p]), fmaxf(wred[2][p], wred[3][p]));
  __syncthreads();  // wred reuse
#pragma unroll
  for (int p = 0; p < 4; ++p) {
    float e = expf(sc[p] - bm[p]);
    for (int off = 32; off > 0; off >>= 1) e += __shfl_down(e, off);
    if (lane == 0) wred[wave][p] = e;
  }
  __syncthreads();
  if (t < 4) {
    float s = wred[0][t] + wred[1][t] + wred[2][t] + wred[3][t];
    partials[(size_t)(bh * 4 + t) * NCHUNK + blockIdx.x] = make_float2(bm[t], s);
  }
}

// ---------------------------------------------------------------------------
// Kernel 3: top-384 radix-select + hybrid register bitonic sort.
// [byte-identical to the 229us baseline]
// ---------------------------------------------------------------------------
__global__ __launch_bounds__(256) void k3_topk(
    const float* __restrict__ tk, int* __restrict__ indices) {
  int bh = blockIdx.x;
  int t = threadIdx.x;
  int lane = t & 63;
  __shared__ unsigned us[4096];
  __shared__ unsigned hist[2048];
  __shared__ unsigned long long binlist[2048];
  __shared__ unsigned long long selk[512];
  __shared__ unsigned chunkSum[32];
  __shared__ int c1, c2, binB_s, nAbove_s, needed_s;

  {
    const float4* tk4 = (const float4*)(tk + (bh << 12));
    for (int i = t; i < 1024; i += 256) {
      float4 v = tk4[i];
      unsigned b0 = __float_as_uint(v.x), b1 = __float_as_uint(v.y);
      unsigned b2 = __float_as_uint(v.z), b3 = __float_as_uint(v.w);
      us[i * 4 + 0] = (b0 & 0x80000000u) ? ~b0 : (b0 | 0x80000000u);
      us[i * 4 + 1] = (b1 & 0x80000000u) ? ~b1 : (b1 | 0x80000000u);
      us[i * 4 + 2] = (b2 & 0x80000000u) ? ~b2 : (b2 | 0x80000000u);
      us[i * 4 + 3] = (b3 & 0x80000000u) ? ~b3 : (b3 | 0x80000000u);
    }
  }
  for (int i = t; i < 2048; i += 256) hist[i] = 0;
  if (t == 0) { c1 = 0; c2 = 0; }
  __syncthreads();

  for (int s = SINKN + t; s < SEQKV - LOCALK; s += 256)
    atomicAdd(&hist[us[s] >> 21], 1u);
  __syncthreads();

  if (t < 32) {
    unsigned sum = 0;
    for (int i = 0; i < 64; ++i) sum += hist[t * 64 + i];
    chunkSum[t] = sum;
  }
  __syncthreads();

  if (t < 64) {
    int l = t;
    unsigned x = (l < 32) ? chunkSum[l] : 0;
    unsigned sfx = x;
    for (int off = 1; off < 64; off <<= 1) {
      unsigned y = __shfl_down(sfx, off);
      if (l + off < 64) sfx += y;
    }
    unsigned above = sfx - x;
    bool hit = (l < 32) && (above < NTOP) && (above + x >= NTOP);
    unsigned long long mask = __ballot(hit);
    int C = __ffsll(mask) - 1;
    unsigned aboveC = __shfl(above, C);
    unsigned h = hist[C * 64 + l];
    unsigned sfx2 = h;
    for (int off = 1; off < 64; off <<= 1) {
      unsigned y = __shfl_down(sfx2, off);
      if (l + off < 64) sfx2 += y;
    }
    unsigned above2 = aboveC + (sfx2 - h);
    bool hit2 = (above2 < NTOP) && (above2 + h >= NTOP);
    unsigned long long mask2 = __ballot(hit2);
    int lB = __ffsll(mask2) - 1;
    if (l == lB) {
      binB_s = C * 64 + l;
      nAbove_s = (int)above2;
      needed_s = NTOP - (int)above2;
    }
  }
  __syncthreads();
  unsigned B = (unsigned)binB_s;
  int nAbove = nAbove_s, needed = needed_s;

  for (int s0 = SINKN; s0 < SEQKV - LOCALK; s0 += 256) {
    int s = s0 + t;
    bool valid = (s < SEQKV - LOCALK);
    unsigned u = valid ? us[s] : 0u;
    unsigned bin = u >> 21;
    bool win = valid && (bin > B);
    bool bnd = valid && (bin == B);
    unsigned long long mw = __ballot(win);
    unsigned long long mb = __ballot(bnd);
    int bw = 0, bb = 0;
    if (lane == 0) {
      if (mw) bw = atomicAdd(&c1, __popcll(mw));
      if (mb) bb = atomicAdd(&c2, __popcll(mb));
    }
    bw = __shfl(bw, 0);
    bb = __shfl(bb, 0);
    unsigned long long lmask = (1ULL << lane) - 1ULL;
    unsigned long long key = ((unsigned long long)u << 32) | (unsigned)(~s);
    if (win) selk[bw + __popcll(mw & lmask)] = key;
    if (bnd) {
      int pos = bb + __popcll(mb & lmask);
      if (pos < 2048) binlist[pos] = key;
    }
  }
  __syncthreads();
  int m2 = c2;
  int p2 = 1;
  while (p2 < m2) p2 <<= 1;
  for (int i = m2 + t; i < p2; i += 256) binlist[i] = 0ULL;
  __syncthreads();
  for (int k = 2; k <= p2; k <<= 1)
    for (int j = k >> 1; j > 0; j >>= 1) {
      for (int i = t; i < p2; i += 256) {
        int ixj = i ^ j;
        if (ixj > i) {
          bool desc = ((i & k) == 0);
          unsigned long long a = binlist[i], bb2 = binlist[ixj];
          if ((a < bb2) == desc) { binlist[i] = bb2; binlist[ixj] = a; }
        }
      }
      __syncthreads();
    }
  for (int i = t; i < needed; i += 256) selk[nAbove + i] = binlist[i];
  for (int i = NTOP + t; i < 512; i += 256) selk[i] = 0ULL;
  __syncthreads();

  unsigned long long e0 = selk[t], e1 = selk[t + 256];
  int i1 = t + 256;
  for (int k = 2; k <= 512; k <<= 1) {
    for (int j = k >> 1; j > 0; j >>= 1) {
      if (j == 256) {
        if (e0 < e1) { unsigned long long tmp = e0; e0 = e1; e1 = tmp; }
      } else if (j >= 64) {
        selk[t] = e0; selk[i1] = e1;
        __syncthreads();
        unsigned long long p0 = selk[t ^ j], p1 = selk[i1 ^ j];
        __syncthreads();
        bool d0 = ((t & k) == 0), l0 = ((t & j) == 0);
        e0 = (d0 == l0) ? (e0 > p0 ? e0 : p0) : (e0 < p0 ? e0 : p0);
        bool d1 = ((i1 & k) == 0), l1 = ((i1 & j) == 0);
        e1 = (d1 == l1) ? (e1 > p1 ? e1 : p1) : (e1 < p1 ? e1 : p1);
      } else {
        unsigned long long p0 = __shfl_xor(e0, j);
        unsigned long long p1 = __shfl_xor(e1, j);
        bool d0 = ((t & k) == 0), l0 = ((t & j) == 0);
        e0 = (d0 == l0) ? (e0 > p0 ? e0 : p0) : (e0 < p0 ? e0 : p0);
        bool d1 = ((i1 & k) == 0);
        e1 = (d1 == l0) ? (e1 > p1 ? e1 : p1) : (e1 < p1 ? e1 : p1);
      }
    }
  }

  if (t < SINKN) indices[bh * KSEL + t] = t;
  for (int i = t; i < LOCALK; i += 256)
    indices[bh * KSEL + SINKN + i] = (SEQKV - LOCALK) + i;
  indices[bh * KSEL + NMASK + t] = (int)(~(unsigned)(e0 & 0xFFFFFFFFu));
  if (t < NTOP - 256)
    indices[bh * KSEL + NMASK + 256 + t] = (int)(~(unsigned)(e1 & 0xFFFFFFFFu));
}

// ---------------------------------------------------------------------------
// Kernel 5: gathered QK^T. grid (26, 32 bh), block 256 = 4 waves.
// MLP restructure: the 5 gathered K-row float2 loads are issued back-to-back
// into registers BEFORE any reduction (1 HBM latency round instead of 5).
// All loads in-bounds: j>=KSEL lanes read the (valid) current-key row.
// ---------------------------------------------------------------------------
__global__ __launch_bounds__(256) void k5_qk(
    const float* __restrict__ q, const float* __restrict__ key,
    const float* __restrict__ lm, const float* __restrict__ key_cpu,
    const int* __restrict__ indices, float* __restrict__ s2_g) {
  int bh = blockIdx.y;
  int t = threadIdx.x;
  int wave = t >> 6, lane = t & 63;
  __shared__ float qs[512];
  __shared__ int sidx[KSEL];
  qs[t] = q[((size_t)bh * 4 << 7) + t];
  qs[t + 256] = q[((size_t)bh * 4 << 7) + t + 256];
  for (int j = t; j < KSEL; j += 256) sidx[j] = indices[bh * KSEL + j];
  __syncthreads();

  const float rsqd = 0.08838834764831845f;  // 1/sqrt(128)
  float q0a = qs[lane * 2], q0b = qs[lane * 2 + 1];
  float q1a = qs[128 + lane * 2], q1b = qs[128 + lane * 2 + 1];
  float q2a = qs[256 + lane * 2], q2b = qs[256 + lane * 2 + 1];
  float q3a = qs[384 + lane * 2], q3b = qs[384 + lane * 2 + 1];

  // phase A: compute row pointers and issue all 5 loads (independent)
  int jv[5], sjv[5];
  float2 kk[5];
#pragma unroll
  for (int i = 0; i < 5; ++i) {
    int j = (blockIdx.x << 2) + wave + 104 * i;
    jv[i] = j;
    int sj = SEQKV;
    const float* krow = key + ((size_t)bh << 7);
    if (j < KSEL) {
      sj = sidx[j];
      krow = key_cpu + ((((size_t)bh << 12) + sj) << 7);
    }
    sjv[i] = sj;
    kk[i] = ((const float2*)krow)[lane];
  }

  // phase B: reductions + stores
#pragma unroll
  for (int i = 0; i < 5; ++i) {
    int j = jv[i];
    if (j > KSEL) continue;
    float2 kv = kk[i];
    float p0 = q0a * kv.x + q0b * kv.y;
    float p1 = q1a * kv.x + q1b * kv.y;
    float p2 = q2a * kv.x + q2b * kv.y;
    float p3 = q3a * kv.x + q3b * kv.y;
    for (int off = 32; off > 0; off >>= 1) {
      p0 += __shfl_down(p0, off);
      p1 += __shfl_down(p1, off);
      p2 += __shfl_down(p2, off);
      p3 += __shfl_down(p3, off);
    }
    if (lane == 0) {
      size_t lmb = (size_t)bh * 4 * SEQN + sjv[i];
      s2_g[(bh * 4 + 0) * 520 + j] = p0 * rsqd + lm[lmb + 0 * SEQN];
      s2_g[(bh * 4 + 1) * 520 + j] = p1 * rsqd + lm[lmb + 1 * SEQN];
      s2_g[(bh * 4 + 2) * 520 + j] = p2 * rsqd + lm[lmb + 2 * SEQN];
      s2_g[(bh * 4 + 3) * 520 + j] = p3 * rsqd + lm[lmb + 3 * SEQN];
    }
  }
}

// ---------------------------------------------------------------------------
// Kernel 6: per (bh,p) stats + softmax + out init. grid 128, block 256.
// [byte-identical to the 229us baseline]
// ---------------------------------------------------------------------------
__global__ __launch_bounds__(256) void k6_stats(
    const float* __restrict__ scores, const float2* __restrict__ partials,
    const int* __restrict__ indices, const float* __restrict__ s2_g,
    const float* __restrict__ value, const float* __restrict__ mean_v,
    float* __restrict__ out_w, float* __restrict__ w_g,
    float* __restrict__ out) {
  int bhp = blockIdx.x;
  int bh = bhp >> 2;
  int t = threadIdx.x;
  __shared__ int sidx[KSEL];
  __shared__ float red[256];
  __shared__ float bc;

  for (int j = t; j < KSEL; j += 256) sidx[j] = indices[bh * KSEL + j];
  __syncthreads();

  const float* srow = scores + (size_t)bhp * SSTR;
  float cur = srow[SEQKV];

  float m = cur, sumexp;
  {
    float2 pc[NCHUNK];
#pragma unroll
    for (int c = 0; c < NCHUNK; ++c) {
      pc[c] = partials[(size_t)bhp * NCHUNK + c];
      m = fmaxf(m, pc[c].x);
    }
    float s = expf(cur - m);
#pragma unroll
    for (int c = 0; c < NCHUNK; ++c) s += pc[c].y * expf(pc[c].x - m);
    sumexp = s;
  }

  float ss = 0.f;
  for (int j = t; j < KSEL; j += 256) ss += expf(srow[sidx[j]] - m);
  red[t] = ss; __syncthreads();
  for (int st = 128; st > 0; st >>= 1) {
    if (t < st) red[t] += red[t + st];
    __syncthreads();
  }
  float kvw;
  if (t == 0) bc = (red[0] + expf(cur - m)) / sumexp;
  __syncthreads();
  kvw = bc; __syncthreads();

  const float* s2r = s2_g + (size_t)bhp * 520;
  float mx2 = -INFINITY;
  for (int j = t; j < KSEL + 1; j += 256) mx2 = fmaxf(mx2, s2r[j]);
  red[t] = mx2; __syncthreads();
  for (int st = 128; st > 0; st >>= 1) {
    if (t < st) red[t] = fmaxf(red[t], red[t + st]);
    __syncthreads();
  }
  float m2 = red[0]; __syncthreads();
  float se2 = 0.f;
  for (int j = t; j < KSEL + 1; j += 256) se2 += expf(s2r[j] - m2);
  red[t] = se2; __syncthreads();
  for (int st = 128; st > 0; st >>= 1) {
    if (t < st) red[t] += red[t + st];
    __syncthreads();
  }
  float inv = kvw / red[0];

  for (int j = t; j < KSEL + 1; j += 256) {
    float w = expf(s2r[j] - m2) * inv;
    out_w[(size_t)bhp * (KSEL + 1) + j] = w;
    w_g[(size_t)bhp * 520 + j] = w;
  }

  if (t < 128) {
    float vcur = value[((size_t)bh << 7) + t];
    float mvn = (mean_v[((size_t)bh << 7) + t] * 4096.f + vcur) / 4097.f;
    out[((size_t)bhp << 7) + t] = (1.f - kvw) * mvn;
  }
}

// ---------------------------------------------------------------------------
// Kernel 7: out += sum_j w[p][j] * V_g[j][:]. grid (17, 32 bh), block 256.
// MLP restructure: main loop manually unrolled 4-deep — 4 independent
// gathered V-rows in flight per pass (vs 1 serial before).
// ---------------------------------------------------------------------------
__global__ __launch_bounds__(256) void k7_wv(
    const float* __restrict__ value, const float* __restrict__ value_cpu,
    const int* __restrict__ indices, const float* __restrict__ w_g,
    float* __restrict__ out) {
  int bh = blockIdx.y;
  int c0 = blockIdx.x << 5;  // chunk start j
  int t = threadIdx.x;
  int d = t & 127, half = t >> 7;
  __shared__ int sidx[32];
  __shared__ float wsh[4][32];
  __shared__ float red[2][4][128];

  int nj = min(32, KSEL + 1 - c0);
  if (t < nj) {
    int j = c0 + t;
    sidx[t] = (j < KSEL) ? indices[bh * KSEL + j] : -1;
  }
  if (t < 128) {
    int p = t >> 5, jl = t & 31;
    wsh[p][jl] = (jl < nj) ? w_g[(size_t)(bh * 4 + p) * 520 + c0 + jl] : 0.f;
  }
  __syncthreads();

  const float* vbase = value_cpu + ((size_t)bh << 19);
  const float* vcurrow = value + ((size_t)bh << 7);
  float a0 = 0, a1 = 0, a2 = 0, a3 = 0;
  int jl = half;
  // 4-deep: rows jl, jl+2, jl+4, jl+6 loaded concurrently
  for (; jl + 6 < nj; jl += 8) {
    int s0 = sidx[jl], s1 = sidx[jl + 2], s2i = sidx[jl + 4], s3 = sidx[jl + 6];
    const float* r0 = (s0 >= 0) ? vbase + ((size_t)s0 << 7) : vcurrow;
    const float* r1 = (s1 >= 0) ? vbase + ((size_t)s1 << 7) : vcurrow;
    const float* r2 = (s2i >= 0) ? vbase + ((size_t)s2i << 7) : vcurrow;
    const float* r3 = (s3 >= 0) ? vbase + ((size_t)s3 << 7) : vcurrow;
    float v0 = r0[d], v1 = r1[d], v2 = r2[d], v3 = r3[d];
    a0 += wsh[0][jl] * v0; a1 += wsh[1][jl] * v0;
    a2 += wsh[2][jl] * v0; a3 += wsh[3][jl] * v0;
    a0 += wsh[0][jl + 2] * v1; a1 += wsh[1][jl + 2] * v1;
    a2 += wsh[2][jl + 2] * v1; a3 += wsh[3][jl + 2] * v1;
    a0 += wsh[0][jl + 4] * v2; a1 += wsh[1][jl + 4] * v2;
    a2 += wsh[2][jl + 4] * v2; a3 += wsh[3][jl + 4] * v2;
    a0 += wsh[0][jl + 6] * v3; a1 += wsh[1][jl + 6] * v3;
    a2 += wsh[2][jl + 6] * v3; a3 += wsh[3][jl + 6] * v3;
  }
  for (; jl < nj; jl += 2) {
    int sj = sidx[jl];
    const float* vrow = (sj >= 0) ? vbase + ((size_t)sj << 7) : vcurrow;
    float v = vrow[d];
    a0 += wsh[0][jl] * v;
    a1 += wsh[1][jl] * v;
    a2 += wsh[2][jl] * v;
    a3 += wsh[3][jl] * v;
  }
  red[half][0][d] = a0; red[half][1][d] = a1;
  red[half][2][d] = a2; red[half][3][d] = a3;
  __syncthreads();
  if (half == 0) {
#pragma unroll
    for (int p = 0; p < 4; ++p) {
      float s = red[0][p][d] + red[1][p][d];
      atomicAdd(&out[(size_t)(bh * 4 + p) * 128 + d], s);
    }
  }
}

// ---------------------------------------------------------------------------
extern "C" void kernel_launch(void* const* d_in, const int* in_sizes, int n_in,
                              void* d_out, int out_size, void* d_ws, size_t ws_size,
                              hipStream_t stream) {
  const float* query     = (const float*)d_in[0];
  const float* key       = (const float*)d_in[1];
  const float* value     = (const float*)d_in[2];
  const float* logmask   = (const float*)d_in[3];
  const float* key_cpu   = (const float*)d_in[4];
  const float* value_cpu = (const float*)d_in[5];
  const float* s_key_cpu = (const float*)d_in[6];
  const float* mean_v    = (const float*)d_in[7];

  float* out   = (float*)d_out;       // (4,32,1,128) = 16384 floats
  float* out_w = out + 16384;         // (4,32,1,517) = 66176 floats

  char* ws = (char*)d_ws;
  int*    indices  = (int*)(ws + 20480);          // 66048 B
  float*  scores   = (float*)(ws + 86528);        // 128*4100*4 = 2099200 B
  float*  tk       = (float*)(ws + 2185728);      // 524288 B
  float*  s2_g     = (float*)(ws + 2710016);      // 266240 B
  float*  w_g      = (float*)(ws + 2976256);      // 266240 B
  float2* partials = (float2*)(ws + 3242496);     // 128*16*8 = 16384 B
  // total ws use: 3,258,880 bytes (proven footprint)

  hipLaunchKernelGGL(k2_scores, dim3(NCHUNK, NBH), dim3(256), 0, stream,
                     query, key, s_key_cpu, logmask, scores, tk, partials);
  hipLaunchKernelGGL(k3_topk, dim3(NBH), dim3(256), 0, stream,
                     tk, indices);
  hipLaunchKernelGGL(k5_qk, dim3(26, NBH), dim3(256), 0, stream,
                     query, key, logmask, key_cpu, indices, s2_g);
  hipLaunchKernelGGL(k6_stats, dim3(128), dim3(256), 0, stream,
                     scores, partials, indices, s2_g, value, mean_v,
                     out_w, w_g, out);
  hipLaunchKernelGGL(k7_wv, dim3(17, NBH), dim3(256), 0, stream,
                     value, value_cpu, indices, w_g, out);
}